// Round 9
// baseline (15.663 us; speedup 1.0000x reference)
//
#include <hip/hip_runtime.h>

static constexpr int HID = 64;
static constexpr int M   = 63;            // intervals; knots 0..63 = one wave
static constexpr int NK  = 64;
static constexpr int TPB = 1024;
static constexpr int OVPT  = 4;           // outputs per thread
static constexpr int OTILE = TPB * OVPT;  // 4096 outputs per block

__device__ __forceinline__ float softplusf(float x) {
  return (x > 20.0f) ? x : log1pf(expf(x));
}

// fast tanh via hardware exp + rcp: tanh(x) = 1 - 2/(e^{2x}+1). rel err ~1e-7.
__device__ __forceinline__ float fast_tanhf(float x) {
  float e = __expf(2.0f * x);
  return 1.0f - 2.0f * __builtin_amdgcn_rcpf(e + 1.0f);
}

// ONE kernel, 123 blocks x 1024 threads, small rolled code (no I$ thrash).
// Each block redundantly computes the 64-knot solution (identical fp32 work
// -> deterministic), then writes its own 4096-output slice.
//  1. W2 -> LDS, one coalesced float4/thread.
//  2. layer 1 TRANSPOSED: h1T[knot][k] (float4 writes) so the GEMM reads h1
//     as b128 rows (no b32 broadcasts anywhere in the hot loop).
//  3. layer2+3 on 4 waves only, 4 knots x 4 units per thread: per 4-k chunk
//     just 8 ds_read_b128 + 64 FMA. LDS instrs cut ~4x vs R8.
//  4. wave 0: 7-phase register Picard (4th-order cumulative quadrature),
//     then Ik[p] = I0*exp(Q_I - g*t_p) into LDS.
//  5. all 1024 threads: cubic-Lagrange interp of Ik (NO exp), float4 stores.
__global__ void __launch_bounds__(TPB)
sir_onekernel(const float* __restrict__ I_init,
              const float* __restrict__ W1, const float* __restrict__ b1,
              const float* __restrict__ W2, const float* __restrict__ b2,
              const float* __restrict__ W3, const float* __restrict__ b3,
              const float* __restrict__ gamma_param,
              float* __restrict__ out, int T) {
  __shared__ float W2s[HID * HID];   // 16 KB
  __shared__ float h1T[NK * HID];    // 16 KB, [knot][k]
  __shared__ float beta_s[NK];
  __shared__ float Ik[NK];

  const int tid = threadIdx.x;
  const float h = 1.0f / (float)M;

  // ---- stage W2 (4096 floats, one float4 per thread) ----
  ((float4*)W2s)[tid] = ((const float4*)W2)[tid];

  // ---- layer 1, transposed: thread -> (knot = tid>>4, k0 = 4*(tid&15)) ----
  {
    const int knot = tid >> 4;
    const int k0   = (tid & 15) * 4;
    const float tv = (float)knot * h;
    float4 w1 = *(const float4*)(W1 + k0);
    float4 bb = *(const float4*)(b1 + k0);
    float4 hv;
    hv.x = fast_tanhf(fmaf(tv, w1.x, bb.x));
    hv.y = fast_tanhf(fmaf(tv, w1.y, bb.y));
    hv.z = fast_tanhf(fmaf(tv, w1.z, bb.z));
    hv.w = fast_tanhf(fmaf(tv, w1.w, bb.w));
    *(float4*)(h1T + knot * HID + k0) = hv;
  }
  __syncthreads();

  // ---- layers 2+3 on threads 0..255 (waves 0-3) ----
  if (tid < 256) {
    const int jq = tid & 15;
    const int j0 = jq * 4;
    const int kg = tid >> 4;            // [0,16): knots {kg, kg+16, kg+32, kg+48}
    float4 bb2 = *(const float4*)(b2 + j0);
    float z[4][4];
#pragma unroll
    for (int q = 0; q < 4; ++q) {
      z[q][0] = bb2.x; z[q][1] = bb2.y; z[q][2] = bb2.z; z[q][3] = bb2.w;
    }
#pragma unroll 4
    for (int kc = 0; kc < HID; kc += 4) {
      float4 aa[4], ww[4];
#pragma unroll
      for (int q = 0; q < 4; ++q)
        aa[q] = *(const float4*)(h1T + (kg + 16 * q) * HID + kc);
#pragma unroll
      for (int c = 0; c < 4; ++c)
        ww[c] = *(const float4*)(W2s + (kc + c) * HID + j0);
#pragma unroll
      for (int c = 0; c < 4; ++c) {
        float4 w = ww[c];
#pragma unroll
        for (int q = 0; q < 4; ++q) {
          float s = (c == 0) ? aa[q].x : (c == 1) ? aa[q].y
                  : (c == 2) ? aa[q].z : aa[q].w;
          z[q][0] = fmaf(s, w.x, z[q][0]);
          z[q][1] = fmaf(s, w.y, z[q][1]);
          z[q][2] = fmaf(s, w.z, z[q][2]);
          z[q][3] = fmaf(s, w.w, z[q][3]);
        }
      }
    }
    float4 w3v = *(const float4*)(W3 + j0);
    float acc[4];
#pragma unroll
    for (int q = 0; q < 4; ++q) {
      acc[q] = fast_tanhf(z[q][0]) * w3v.x + fast_tanhf(z[q][1]) * w3v.y
             + fast_tanhf(z[q][2]) * w3v.z + fast_tanhf(z[q][3]) * w3v.w;
      acc[q] += __shfl_xor(acc[q], 1);
      acc[q] += __shfl_xor(acc[q], 2);
      acc[q] += __shfl_xor(acc[q], 4);
      acc[q] += __shfl_xor(acc[q], 8);
    }
    if (jq == 0) {
      float bb3 = b3[0];
#pragma unroll
      for (int q = 0; q < 4; ++q)
        beta_s[kg + 16 * q] = softplusf(acc[q] + bb3);
    }
  }
  __syncthreads();

  // ---- Picard on wave 0 (serial path, ~0.5 us; others wait) ----
  if (tid < 64) {
    const float I0 = I_init[0];
    const float g  = softplusf(gamma_param[0]);
    const float S0 = 1.0f - I0;
    const int p = tid;
    const float tp = (float)p * h;
    const float bet = beta_s[p];
    const float c24 = h * (1.0f / 24.0f);
    float QA = 0.0f, QB = 0.0f;
    const int im2 = p >= 2 ? p - 2 : 0;
    const int im1 = p >= 1 ? p - 1 : 0;
    const int ip1 = p <= 62 ? p + 1 : 63;
    const int ip2 = p <= 61 ? p + 2 : 63;
    const int ip3 = p <= 60 ? p + 3 : 63;
    for (int ph = 0; ph < 7; ++ph) {
      const bool iPass = (ph & 1) == 0;
      float f = iPass ? (bet * S0 * __expf(-QA))
                      : (bet * I0 * __expf(QB - g * tp));
      float fm2 = __shfl(f, im2);
      float fm1 = __shfl(f, im1);
      float f1  = __shfl(f, ip1);
      float f2  = __shfl(f, ip2);
      float f3  = __shfl(f, ip3);
      float e;
      if (p == 0)       e = 9.0f*f + 19.0f*f1 - 5.0f*f2 + f3;     // AM start
      else if (p < 62)  e = 13.0f*(f + f1) - fm1 - f2;            // interior
      else if (p == 62) e = fm2 - 5.0f*fm1 + 19.0f*f + 9.0f*f1;   // AM end
      else              e = 0.0f;                                 // lane 63
      e *= c24;
      float incl = e;
#pragma unroll
      for (int off = 1; off < 64; off <<= 1) {
        float w = __shfl_up(incl, off);
        if (p >= off) incl += w;
      }
      float Q = incl - e;                    // exclusive prefix = Q at knot p
      if (iPass) QB = Q; else QA = Q;
    }
    Ik[p] = I0 * __expf(QB - g * tp);        // I at knot p
  }
  __syncthreads();

  // ---- output slice: cubic-Lagrange interp of Ik (no exp) ----
  const float scale = (float)M / (float)T;
  int o0 = blockIdx.x * OTILE + tid * OVPT;
  float r[OVPT];
#pragma unroll
  for (int u = 0; u < OVPT; ++u) {
    int i = o0 + u;
    float pos = (float)(i + 1) * scale;            // (0, M]
    int js = (int)pos - 1;
    js = js < 0 ? 0 : (js > M - 3 ? M - 3 : js);   // [0, 60]
    float x = pos - (float)js;                     // [0, 3]
    float xm1 = x - 1.0f, xm2 = x - 2.0f, xm3 = x - 3.0f;
    float w0 = -(xm1 * xm2 * xm3) * (1.0f / 6.0f);
    float w1 =  (x   * xm2 * xm3) * 0.5f;
    float w2 = -(x   * xm1 * xm3) * 0.5f;
    float w3 =  (x   * xm1 * xm2) * (1.0f / 6.0f);
    r[u] = w0 * Ik[js]     + w1 * Ik[js + 1]
         + w2 * Ik[js + 2] + w3 * Ik[js + 3];
  }
  if (o0 + OVPT <= T) {
    *(float4*)(out + o0) = make_float4(r[0], r[1], r[2], r[3]);
  } else {
#pragma unroll
    for (int u = 0; u < OVPT; ++u) {
      int i = o0 + u;
      if (i < T) out[i] = r[u];
    }
  }
}

extern "C" void kernel_launch(void* const* d_in, const int* in_sizes, int n_in,
                              void* d_out, int out_size, void* d_ws, size_t ws_size,
                              hipStream_t stream) {
  const float* I0 = (const float*)d_in[1];
  const float* W1 = (const float*)d_in[2];
  const float* b1 = (const float*)d_in[3];
  const float* W2 = (const float*)d_in[4];
  const float* b2 = (const float*)d_in[5];
  const float* W3 = (const float*)d_in[6];
  const float* b3 = (const float*)d_in[7];
  const float* gp = (const float*)d_in[8];
  float* out = (float*)d_out;
  int T = in_sizes[0];

  int blocks = (T + OTILE - 1) / OTILE;            // 123
  hipLaunchKernelGGL(sir_onekernel, dim3(blocks), dim3(TPB), 0, stream,
                     I0, W1, b1, W2, b2, W3, b3, gp, out, T);
}

// Round 10
// 14.355 us; speedup vs baseline: 1.0911x; 1.0911x over previous
//
#include <hip/hip_runtime.h>

static constexpr int HID = 64;
static constexpr int M   = 63;            // intervals; knots 0..63 = one wave
static constexpr int NK  = 64;
static constexpr int TPB = 1024;
static constexpr int OVPT  = 4;           // outputs per thread
static constexpr int OTILE = TPB * OVPT;  // 4096 outputs per block

__device__ __forceinline__ float softplusf(float x) {
  return (x > 20.0f) ? x : log1pf(expf(x));
}

// fast tanh via hardware exp + rcp: tanh(x) = 1 - 2/(e^{2x}+1). rel err ~1e-7.
__device__ __forceinline__ float fast_tanhf(float x) {
  float e = __expf(2.0f * x);
  return 1.0f - 2.0f * __builtin_amdgcn_rcpf(e + 1.0f);
}

// ONE kernel, 123 blocks x 1024 threads — the R8 structure (measured best),
// with ONE change: the Picard tail stores I at the knots, so the output
// stage is a pure cubic interp (no exp). Small rolled code throughout.
//  1. W2 -> LDS in one fully-parallel coalesced float4 round (16 KB).
//  2. h1T[k][knot] = tanh(t*W1+b1) transposed in LDS.
//  3. layer2+3 on all 16 waves: per k, 1 b32 broadcast + 1 b128 (2-way free).
//  4. wave 0: 7-phase register Picard (4th-order cumulative quadrature),
//     writes Ik[p] = I0*exp(Q_I(t_p) - g*t_p) to LDS.
//  5. all threads: cubic-Lagrange interp of Ik, float4 stores.
__global__ void __launch_bounds__(TPB)
sir_onekernel(const float* __restrict__ I_init,
              const float* __restrict__ W1, const float* __restrict__ b1,
              const float* __restrict__ W2, const float* __restrict__ b2,
              const float* __restrict__ W3, const float* __restrict__ b3,
              const float* __restrict__ gamma_param,
              float* __restrict__ out, int T) {
  __shared__ float W2s[HID * HID];   // 16 KB
  __shared__ float h1T[HID * NK];    // 16 KB, [k][knot]
  __shared__ float beta_s[NK];
  __shared__ float Ik[NK];

  const int tid = threadIdx.x;
  const float h = 1.0f / (float)M;

  // ---- stage W2: one coalesced float4 per thread (4096 floats) ----
  ((float4*)W2s)[tid] = ((const float4*)W2)[tid];

  // ---- layer 1: consecutive tid -> consecutive LDS addr, conflict-free ----
#pragma unroll
  for (int r = 0; r < 4; ++r) {
    int idx = r * 1024 + tid;
    int k = idx >> 6;
    int knot = idx & 63;
    h1T[idx] = fast_tanhf(fmaf((float)knot * h, W1[k], b1[k]));
  }
  __syncthreads();

  // ---- layers 2+3: thread -> (knot = tid>>4, 4 units j0 = 4*(tid&15)) ----
  {
    const int knot = tid >> 4;
    const int jq   = tid & 15;
    const int j0   = jq * 4;
    float4 bb = *(const float4*)(b2 + j0);
    float z0 = bb.x, z1 = bb.y, z2 = bb.z, z3 = bb.w;
#pragma unroll 8
    for (int k = 0; k < HID; ++k) {
      float hk = h1T[k * NK + knot];                   // broadcast
      float4 w = *(const float4*)(W2s + k * HID + j0); // 16 addrs, 2-way free
      z0 = fmaf(hk, w.x, z0); z1 = fmaf(hk, w.y, z1);
      z2 = fmaf(hk, w.z, z2); z3 = fmaf(hk, w.w, z3);
    }
    float4 w3v = *(const float4*)(W3 + j0);
    float acc = fast_tanhf(z0) * w3v.x + fast_tanhf(z1) * w3v.y
              + fast_tanhf(z2) * w3v.z + fast_tanhf(z3) * w3v.w;
    acc += __shfl_xor(acc, 1);
    acc += __shfl_xor(acc, 2);
    acc += __shfl_xor(acc, 4);
    acc += __shfl_xor(acc, 8);
    if (jq == 0) beta_s[knot] = softplusf(acc + b3[0]);
  }
  __syncthreads();

  // ---- Picard on wave 0 (serial path; other waves wait at the barrier) ----
  if (tid < 64) {
    const float I0 = I_init[0];
    const float g  = softplusf(gamma_param[0]);
    const float S0 = 1.0f - I0;
    const int p = tid;
    const float tp = (float)p * h;
    const float bet = beta_s[p];
    const float c24 = h * (1.0f / 24.0f);
    float QA = 0.0f, QB = 0.0f;
    const int im2 = p >= 2 ? p - 2 : 0;
    const int im1 = p >= 1 ? p - 1 : 0;
    const int ip1 = p <= 62 ? p + 1 : 63;
    const int ip2 = p <= 61 ? p + 2 : 63;
    const int ip3 = p <= 60 ? p + 3 : 63;
    for (int ph = 0; ph < 7; ++ph) {
      const bool iPass = (ph & 1) == 0;
      float f = iPass ? (bet * S0 * __expf(-QA))
                      : (bet * I0 * __expf(QB - g * tp));
      float fm2 = __shfl(f, im2);
      float fm1 = __shfl(f, im1);
      float f1  = __shfl(f, ip1);
      float f2  = __shfl(f, ip2);
      float f3  = __shfl(f, ip3);
      float e;
      if (p == 0)       e = 9.0f*f + 19.0f*f1 - 5.0f*f2 + f3;     // AM start
      else if (p < 62)  e = 13.0f*(f + f1) - fm1 - f2;            // interior
      else if (p == 62) e = fm2 - 5.0f*fm1 + 19.0f*f + 9.0f*f1;   // AM end
      else              e = 0.0f;                                 // lane 63
      e *= c24;
      float incl = e;
#pragma unroll
      for (int off = 1; off < 64; off <<= 1) {
        float w = __shfl_up(incl, off);
        if (p >= off) incl += w;
      }
      float Q = incl - e;                    // exclusive prefix = Q at knot p
      if (iPass) QB = Q; else QA = Q;
    }
    Ik[p] = I0 * __expf(QB - g * tp);        // I at knot p (exp folded here)
  }
  __syncthreads();

  // ---- output slice: cubic-Lagrange interp of Ik (no exp) ----
  const float scale = (float)M / (float)T;
  int o0 = blockIdx.x * OTILE + tid * OVPT;
  float r[OVPT];
#pragma unroll
  for (int u = 0; u < OVPT; ++u) {
    int i = o0 + u;
    float pos = (float)(i + 1) * scale;            // (0, M]
    int js = (int)pos - 1;
    js = js < 0 ? 0 : (js > M - 3 ? M - 3 : js);   // [0, 60]
    float x = pos - (float)js;                     // [0, 3]
    float xm1 = x - 1.0f, xm2 = x - 2.0f, xm3 = x - 3.0f;
    float w0 = -(xm1 * xm2 * xm3) * (1.0f / 6.0f);
    float w1 =  (x   * xm2 * xm3) * 0.5f;
    float w2 = -(x   * xm1 * xm3) * 0.5f;
    float w3 =  (x   * xm1 * xm2) * (1.0f / 6.0f);
    r[u] = w0 * Ik[js]     + w1 * Ik[js + 1]
         + w2 * Ik[js + 2] + w3 * Ik[js + 3];
  }
  if (o0 + OVPT <= T) {
    *(float4*)(out + o0) = make_float4(r[0], r[1], r[2], r[3]);
  } else {
#pragma unroll
    for (int u = 0; u < OVPT; ++u) {
      int i = o0 + u;
      if (i < T) out[i] = r[u];
    }
  }
}

extern "C" void kernel_launch(void* const* d_in, const int* in_sizes, int n_in,
                              void* d_out, int out_size, void* d_ws, size_t ws_size,
                              hipStream_t stream) {
  const float* I0 = (const float*)d_in[1];
  const float* W1 = (const float*)d_in[2];
  const float* b1 = (const float*)d_in[3];
  const float* W2 = (const float*)d_in[4];
  const float* b2 = (const float*)d_in[5];
  const float* W3 = (const float*)d_in[6];
  const float* b3 = (const float*)d_in[7];
  const float* gp = (const float*)d_in[8];
  float* out = (float*)d_out;
  int T = in_sizes[0];

  int blocks = (T + OTILE - 1) / OTILE;            // 123
  hipLaunchKernelGGL(sir_onekernel, dim3(blocks), dim3(TPB), 0, stream,
                     I0, W1, b1, W2, b2, W3, b3, gp, out, T);
}

// Round 11
// 13.952 us; speedup vs baseline: 1.1226x; 1.0289x over previous
//
#include <hip/hip_runtime.h>

static constexpr int HID = 64;
static constexpr int M   = 63;            // intervals; knots 0..63 = one wave
static constexpr int NK  = 64;
static constexpr int TPB = 512;           // 8 waves = 2/SIMD
static constexpr int OVPT  = 4;           // outputs per thread
static constexpr int OTILE = TPB * OVPT;  // 2048 outputs per block

__device__ __forceinline__ float softplusf(float x) {
  return (x > 20.0f) ? x : log1pf(expf(x));
}

// fast tanh via hardware exp + rcp: tanh(x) = 1 - 2/(e^{2x}+1). rel err ~1e-7.
__device__ __forceinline__ float fast_tanhf(float x) {
  float e = __expf(2.0f * x);
  return 1.0f - 2.0f * __builtin_amdgcn_rcpf(e + 1.0f);
}

// ONE kernel, 245 blocks x 512 threads (1 block/CU chip-wide), small rolled
// code. Each block redundantly computes the 64-knot solution (identical fp32
// work -> deterministic), then writes its own 2048-output slice.
//  1. W2 -> LDS, two coalesced float4 per thread.
//  2. h1T[k][knot] = tanh(t*W1+b1), 8 knots/thread, float4 writes.
//  3. layer2+3: thread = (2 knots kg/kg+32, 4 units): per k-iter 2 broadcast
//     b32 + 1 b128 (2-way aliased = free) + 8 FMA. Halves LDS instrs AND
//     W2 re-read bytes vs the 16-wave layout; keeps 2 waves/SIMD for latency.
//  4. wave 0: 7-phase register Picard (4th-order cumulative quadrature),
//     writes Ik[p] = I0*exp(Q_I(t_p) - g*t_p) to LDS.
//  5. all threads: cubic-Lagrange interp of Ik (no exp), float4 stores.
__global__ void __launch_bounds__(TPB)
sir_onekernel(const float* __restrict__ I_init,
              const float* __restrict__ W1, const float* __restrict__ b1,
              const float* __restrict__ W2, const float* __restrict__ b2,
              const float* __restrict__ W3, const float* __restrict__ b3,
              const float* __restrict__ gamma_param,
              float* __restrict__ out, int T) {
  __shared__ float W2s[HID * HID];   // 16 KB
  __shared__ float h1T[HID * NK];    // 16 KB, [k][knot]
  __shared__ float beta_s[NK];
  __shared__ float Ik[NK];

  const int tid = threadIdx.x;
  const float h = 1.0f / (float)M;

  // ---- stage W2: two coalesced float4 per thread (4096 floats) ----
  ((float4*)W2s)[tid]       = ((const float4*)W2)[tid];
  ((float4*)W2s)[tid + 512] = ((const float4*)W2)[tid + 512];

  // ---- layer 1: thread -> (k = tid>>3, knots kn0..kn0+7), float4 writes ----
  {
    const int k   = tid >> 3;
    const int kn0 = (tid & 7) * 8;
    const float w1 = W1[k];
    const float bb = b1[k];
    float hv[8];
#pragma unroll
    for (int c = 0; c < 8; ++c)
      hv[c] = fast_tanhf(fmaf((float)(kn0 + c) * h, w1, bb));
    *(float4*)(h1T + k * NK + kn0)     = make_float4(hv[0], hv[1], hv[2], hv[3]);
    *(float4*)(h1T + k * NK + kn0 + 4) = make_float4(hv[4], hv[5], hv[6], hv[7]);
  }
  __syncthreads();

  // ---- layers 2+3: thread -> (knots kg & kg+32, units j0..j0+3) ----
  {
    const int kg = tid >> 4;            // [0,32)
    const int jq = tid & 15;
    const int j0 = jq * 4;
    float4 bb2 = *(const float4*)(b2 + j0);
    float za0 = bb2.x, za1 = bb2.y, za2 = bb2.z, za3 = bb2.w;
    float zb0 = bb2.x, zb1 = bb2.y, zb2 = bb2.z, zb3 = bb2.w;
#pragma unroll 8
    for (int k = 0; k < HID; ++k) {
      float ha = h1T[k * NK + kg];                     // broadcast (4 addrs/wave)
      float hb = h1T[k * NK + kg + 32];                // broadcast
      float4 w = *(const float4*)(W2s + k * HID + j0); // 16 addrs x4 lanes: 2-way free
      za0 = fmaf(ha, w.x, za0); za1 = fmaf(ha, w.y, za1);
      za2 = fmaf(ha, w.z, za2); za3 = fmaf(ha, w.w, za3);
      zb0 = fmaf(hb, w.x, zb0); zb1 = fmaf(hb, w.y, zb1);
      zb2 = fmaf(hb, w.z, zb2); zb3 = fmaf(hb, w.w, zb3);
    }
    float4 w3v = *(const float4*)(W3 + j0);
    float acca = fast_tanhf(za0) * w3v.x + fast_tanhf(za1) * w3v.y
               + fast_tanhf(za2) * w3v.z + fast_tanhf(za3) * w3v.w;
    float accb = fast_tanhf(zb0) * w3v.x + fast_tanhf(zb1) * w3v.y
               + fast_tanhf(zb2) * w3v.z + fast_tanhf(zb3) * w3v.w;
    acca += __shfl_xor(acca, 1); accb += __shfl_xor(accb, 1);
    acca += __shfl_xor(acca, 2); accb += __shfl_xor(accb, 2);
    acca += __shfl_xor(acca, 4); accb += __shfl_xor(accb, 4);
    acca += __shfl_xor(acca, 8); accb += __shfl_xor(accb, 8);
    if (jq == 0) {
      float bb3 = b3[0];
      beta_s[kg]      = softplusf(acca + bb3);
      beta_s[kg + 32] = softplusf(accb + bb3);
    }
  }
  __syncthreads();

  // ---- Picard on wave 0 (serial path; other waves wait at the barrier) ----
  if (tid < 64) {
    const float I0 = I_init[0];
    const float g  = softplusf(gamma_param[0]);
    const float S0 = 1.0f - I0;
    const int p = tid;
    const float tp = (float)p * h;
    const float bet = beta_s[p];
    const float c24 = h * (1.0f / 24.0f);
    float QA = 0.0f, QB = 0.0f;
    const int im2 = p >= 2 ? p - 2 : 0;
    const int im1 = p >= 1 ? p - 1 : 0;
    const int ip1 = p <= 62 ? p + 1 : 63;
    const int ip2 = p <= 61 ? p + 2 : 63;
    const int ip3 = p <= 60 ? p + 3 : 63;
    for (int ph = 0; ph < 7; ++ph) {
      const bool iPass = (ph & 1) == 0;
      float f = iPass ? (bet * S0 * __expf(-QA))
                      : (bet * I0 * __expf(QB - g * tp));
      float fm2 = __shfl(f, im2);
      float fm1 = __shfl(f, im1);
      float f1  = __shfl(f, ip1);
      float f2  = __shfl(f, ip2);
      float f3  = __shfl(f, ip3);
      float e;
      if (p == 0)       e = 9.0f*f + 19.0f*f1 - 5.0f*f2 + f3;     // AM start
      else if (p < 62)  e = 13.0f*(f + f1) - fm1 - f2;            // interior
      else if (p == 62) e = fm2 - 5.0f*fm1 + 19.0f*f + 9.0f*f1;   // AM end
      else              e = 0.0f;                                 // lane 63
      e *= c24;
      float incl = e;
#pragma unroll
      for (int off = 1; off < 64; off <<= 1) {
        float w = __shfl_up(incl, off);
        if (p >= off) incl += w;
      }
      float Q = incl - e;                    // exclusive prefix = Q at knot p
      if (iPass) QB = Q; else QA = Q;
    }
    Ik[p] = I0 * __expf(QB - g * tp);        // I at knot p (exp folded here)
  }
  __syncthreads();

  // ---- output slice: cubic-Lagrange interp of Ik (no exp) ----
  const float scale = (float)M / (float)T;
  int o0 = blockIdx.x * OTILE + tid * OVPT;
  float r[OVPT];
#pragma unroll
  for (int u = 0; u < OVPT; ++u) {
    int i = o0 + u;
    float pos = (float)(i + 1) * scale;            // (0, M]
    int js = (int)pos - 1;
    js = js < 0 ? 0 : (js > M - 3 ? M - 3 : js);   // [0, 60]
    float x = pos - (float)js;                     // [0, 3]
    float xm1 = x - 1.0f, xm2 = x - 2.0f, xm3 = x - 3.0f;
    float w0 = -(xm1 * xm2 * xm3) * (1.0f / 6.0f);
    float w1 =  (x   * xm2 * xm3) * 0.5f;
    float w2 = -(x   * xm1 * xm3) * 0.5f;
    float w3 =  (x   * xm1 * xm2) * (1.0f / 6.0f);
    r[u] = w0 * Ik[js]     + w1 * Ik[js + 1]
         + w2 * Ik[js + 2] + w3 * Ik[js + 3];
  }
  if (o0 + OVPT <= T) {
    *(float4*)(out + o0) = make_float4(r[0], r[1], r[2], r[3]);
  } else {
#pragma unroll
    for (int u = 0; u < OVPT; ++u) {
      int i = o0 + u;
      if (i < T) out[i] = r[u];
    }
  }
}

extern "C" void kernel_launch(void* const* d_in, const int* in_sizes, int n_in,
                              void* d_out, int out_size, void* d_ws, size_t ws_size,
                              hipStream_t stream) {
  const float* I0 = (const float*)d_in[1];
  const float* W1 = (const float*)d_in[2];
  const float* b1 = (const float*)d_in[3];
  const float* W2 = (const float*)d_in[4];
  const float* b2 = (const float*)d_in[5];
  const float* W3 = (const float*)d_in[6];
  const float* b3 = (const float*)d_in[7];
  const float* gp = (const float*)d_in[8];
  float* out = (float*)d_out;
  int T = in_sizes[0];

  int blocks = (T + OTILE - 1) / OTILE;            // 245
  hipLaunchKernelGGL(sir_onekernel, dim3(blocks), dim3(TPB), 0, stream,
                     I0, W1, b1, W2, b2, W3, b3, gp, out, T);
}

// Round 12
// 12.196 us; speedup vs baseline: 1.2842x; 1.1440x over previous
//
#include <hip/hip_runtime.h>

static constexpr int HID = 64;
static constexpr int M   = 31;            // intervals; knots 0..31 = half wave
static constexpr int NK  = 32;
static constexpr int TPB = 512;           // 8 waves = 2/SIMD
static constexpr int OVPT  = 4;           // outputs per thread
static constexpr int OTILE = TPB * OVPT;  // 2048 outputs per block

__device__ __forceinline__ float softplusf(float x) {
  return (x > 20.0f) ? x : log1pf(expf(x));
}

// fast tanh via hardware exp + rcp: tanh(x) = 1 - 2/(e^{2x}+1). rel err ~1e-7.
__device__ __forceinline__ float fast_tanhf(float x) {
  float e = __expf(2.0f * x);
  return 1.0f - 2.0f * __builtin_amdgcn_rcpf(e + 1.0f);
}

// ONE kernel, 245 blocks x 512 threads — R11 structure with M halved to 31
// (4th-order quadrature error ~1e-5, 100x under budget; absmax has sat at the
// bf16 floor for 10 rounds). Each block redundantly computes the 32-knot
// solution (identical fp32 work -> deterministic), writes its 2048-out slice.
//  1. W2 -> LDS, two coalesced float4 per thread.
//  2. h1T[k][knot] = tanh(t*W1+b1), thread = (k, 4 knots), float4 write.
//  3. layer2+3: thread = (1 knot, 4 units): per k-iter 1 broadcast b32 +
//     1 b128 (2-way aliased = free) + 4 FMA; 1024 LDS instrs/block (was 1536).
//  4. half-wave 0: 7-phase register Picard (4th-order cumulative quadrature),
//     writes Ik[p] = I0*exp(Q_I(t_p) - g*t_p) to LDS.
//  5. all threads: cubic-Lagrange interp of Ik (no exp), float4 stores.
__global__ void __launch_bounds__(TPB)
sir_onekernel(const float* __restrict__ I_init,
              const float* __restrict__ W1, const float* __restrict__ b1,
              const float* __restrict__ W2, const float* __restrict__ b2,
              const float* __restrict__ W3, const float* __restrict__ b3,
              const float* __restrict__ gamma_param,
              float* __restrict__ out, int T) {
  __shared__ float W2s[HID * HID];   // 16 KB
  __shared__ float h1T[HID * NK];    // 8 KB, [k][knot]
  __shared__ float beta_s[NK];
  __shared__ float Ik[NK];

  const int tid = threadIdx.x;
  const float h = 1.0f / (float)M;

  // ---- stage W2: two coalesced float4 per thread (4096 floats) ----
  ((float4*)W2s)[tid]       = ((const float4*)W2)[tid];
  ((float4*)W2s)[tid + 512] = ((const float4*)W2)[tid + 512];

  // ---- layer 1: thread -> (k = tid>>3, knots kn0..kn0+3), float4 write ----
  {
    const int k   = tid >> 3;                  // [0,64)
    const int kn0 = (tid & 7) * 4;             // [0,32)
    const float w1 = W1[k];
    const float bb = b1[k];
    float4 hv;
    hv.x = fast_tanhf(fmaf((float)(kn0 + 0) * h, w1, bb));
    hv.y = fast_tanhf(fmaf((float)(kn0 + 1) * h, w1, bb));
    hv.z = fast_tanhf(fmaf((float)(kn0 + 2) * h, w1, bb));
    hv.w = fast_tanhf(fmaf((float)(kn0 + 3) * h, w1, bb));
    *(float4*)(h1T + k * NK + kn0) = hv;
  }
  __syncthreads();

  // ---- layers 2+3: thread -> (knot kg, units j0..j0+3) ----
  {
    const int kg = tid >> 4;            // [0,32)
    const int jq = tid & 15;
    const int j0 = jq * 4;
    float4 bb2 = *(const float4*)(b2 + j0);
    float z0 = bb2.x, z1 = bb2.y, z2 = bb2.z, z3 = bb2.w;
#pragma unroll 8
    for (int k = 0; k < HID; ++k) {
      float hk = h1T[k * NK + kg];                     // broadcast (4 addrs/wave)
      float4 w = *(const float4*)(W2s + k * HID + j0); // 16 addrs x4 lanes: free
      z0 = fmaf(hk, w.x, z0); z1 = fmaf(hk, w.y, z1);
      z2 = fmaf(hk, w.z, z2); z3 = fmaf(hk, w.w, z3);
    }
    float4 w3v = *(const float4*)(W3 + j0);
    float acc = fast_tanhf(z0) * w3v.x + fast_tanhf(z1) * w3v.y
              + fast_tanhf(z2) * w3v.z + fast_tanhf(z3) * w3v.w;
    acc += __shfl_xor(acc, 1);
    acc += __shfl_xor(acc, 2);
    acc += __shfl_xor(acc, 4);
    acc += __shfl_xor(acc, 8);
    if (jq == 0) beta_s[kg] = softplusf(acc + b3[0]);
  }
  __syncthreads();

  // ---- Picard on half-wave 0 (lanes 0..31; serial path, others wait) ----
  if (tid < 32) {
    const float I0 = I_init[0];
    const float g  = softplusf(gamma_param[0]);
    const float S0 = 1.0f - I0;
    const int p = tid;
    const float tp = (float)p * h;
    const float bet = beta_s[p];
    const float c24 = h * (1.0f / 24.0f);
    float QA = 0.0f, QB = 0.0f;
    const int im2 = p >= 2 ? p - 2 : 0;
    const int im1 = p >= 1 ? p - 1 : 0;
    const int ip1 = p <= M - 1 ? p + 1 : M;
    const int ip2 = p <= M - 2 ? p + 2 : M;
    const int ip3 = p <= M - 3 ? p + 3 : M;
    for (int ph = 0; ph < 7; ++ph) {
      const bool iPass = (ph & 1) == 0;
      float f = iPass ? (bet * S0 * __expf(-QA))
                      : (bet * I0 * __expf(QB - g * tp));
      float fm2 = __shfl(f, im2);
      float fm1 = __shfl(f, im1);
      float f1  = __shfl(f, ip1);
      float f2  = __shfl(f, ip2);
      float f3  = __shfl(f, ip3);
      float e;
      if (p == 0)          e = 9.0f*f + 19.0f*f1 - 5.0f*f2 + f3;     // AM start
      else if (p < M - 1)  e = 13.0f*(f + f1) - fm1 - f2;            // interior
      else if (p == M - 1) e = fm2 - 5.0f*fm1 + 19.0f*f + 9.0f*f1;   // AM end
      else                 e = 0.0f;                                 // lane M
      e *= c24;
      float incl = e;
#pragma unroll
      for (int off = 1; off < 32; off <<= 1) {
        float w = __shfl_up(incl, off);
        if (p >= off) incl += w;
      }
      float Q = incl - e;                    // exclusive prefix = Q at knot p
      if (iPass) QB = Q; else QA = Q;
    }
    Ik[p] = I0 * __expf(QB - g * tp);        // I at knot p (exp folded here)
  }
  __syncthreads();

  // ---- output slice: cubic-Lagrange interp of Ik (no exp) ----
  const float scale = (float)M / (float)T;
  int o0 = blockIdx.x * OTILE + tid * OVPT;
  float r[OVPT];
#pragma unroll
  for (int u = 0; u < OVPT; ++u) {
    int i = o0 + u;
    float pos = (float)(i + 1) * scale;            // (0, M]
    int js = (int)pos - 1;
    js = js < 0 ? 0 : (js > M - 3 ? M - 3 : js);   // [0, 28]
    float x = pos - (float)js;                     // [0, 3]
    float xm1 = x - 1.0f, xm2 = x - 2.0f, xm3 = x - 3.0f;
    float w0 = -(xm1 * xm2 * xm3) * (1.0f / 6.0f);
    float w1 =  (x   * xm2 * xm3) * 0.5f;
    float w2 = -(x   * xm1 * xm3) * 0.5f;
    float w3 =  (x   * xm1 * xm2) * (1.0f / 6.0f);
    r[u] = w0 * Ik[js]     + w1 * Ik[js + 1]
         + w2 * Ik[js + 2] + w3 * Ik[js + 3];
  }
  if (o0 + OVPT <= T) {
    *(float4*)(out + o0) = make_float4(r[0], r[1], r[2], r[3]);
  } else {
#pragma unroll
    for (int u = 0; u < OVPT; ++u) {
      int i = o0 + u;
      if (i < T) out[i] = r[u];
    }
  }
}

extern "C" void kernel_launch(void* const* d_in, const int* in_sizes, int n_in,
                              void* d_out, int out_size, void* d_ws, size_t ws_size,
                              hipStream_t stream) {
  const float* I0 = (const float*)d_in[1];
  const float* W1 = (const float*)d_in[2];
  const float* b1 = (const float*)d_in[3];
  const float* W2 = (const float*)d_in[4];
  const float* b2 = (const float*)d_in[5];
  const float* W3 = (const float*)d_in[6];
  const float* b3 = (const float*)d_in[7];
  const float* gp = (const float*)d_in[8];
  float* out = (float*)d_out;
  int T = in_sizes[0];

  int blocks = (T + OTILE - 1) / OTILE;            // 245
  hipLaunchKernelGGL(sir_onekernel, dim3(blocks), dim3(TPB), 0, stream,
                     I0, W1, b1, W2, b2, W3, b3, gp, out, T);
}

// Round 13
// 12.091 us; speedup vs baseline: 1.2954x; 1.0087x over previous
//
#include <hip/hip_runtime.h>

static constexpr int HID = 64;
static constexpr int M   = 31;            // intervals; knots 0..31
static constexpr int NK  = 32;
static constexpr int H1S = 68;            // h1L stride: 64 + 4 pad (bank spread)
static constexpr int TPB = 512;           // 8 waves = 2/SIMD
static constexpr int OVPT  = 4;           // outputs per thread
static constexpr int OTILE = TPB * OVPT;  // 2048 outputs per block

__device__ __forceinline__ float softplusf(float x) {
  return (x > 20.0f) ? x : log1pf(expf(x));
}

// fast tanh via hardware exp + rcp: tanh(x) = 1 - 2/(e^{2x}+1). rel err ~1e-7.
__device__ __forceinline__ float fast_tanhf(float x) {
  float e = __expf(2.0f * x);
  return 1.0f - 2.0f * __builtin_amdgcn_rcpf(e + 1.0f);
}

// ONE kernel, 245 blocks x 512 threads (R12 structure + 2 micro-fixes):
//  1. W2 -> regs FIRST; layer-1 computes while the 16 KB is in flight
//     (async-stage split); then ds_write W2 + one barrier.
//  2. h1 stored TRANSPOSED+padded: h1L[knot*68 + k] -> GEMM reads one b128
//     per 4-k chunk (4 distinct addrs/wave, 4 banks apart: conflict-free
//     broadcast). GEMM per-wave LDS instrs: 128 -> 80.
//  3. layer2+3: thread = (knot kg = tid>>4, units j0 = 4*(tid&15)); per 4-k
//     chunk: 1 h1 b128 + 4 W2 b128 (2-way aliased = free) + 16 FMA.
//  4. half-wave 0: 7-phase register Picard (4th-order cumulative quadrature),
//     writes Ik[p] = I0*exp(Q_I(t_p) - g*t_p) to LDS.
//  5. all threads: cubic-Lagrange interp of Ik (no exp), float4 stores.
__global__ void __launch_bounds__(TPB)
sir_onekernel(const float* __restrict__ I_init,
              const float* __restrict__ W1, const float* __restrict__ b1,
              const float* __restrict__ W2, const float* __restrict__ b2,
              const float* __restrict__ W3, const float* __restrict__ b3,
              const float* __restrict__ gamma_param,
              float* __restrict__ out, int T) {
  __shared__ float W2s[HID * HID];   // 16 KB
  __shared__ float h1L[NK * H1S];    // 8.7 KB, [knot][k] padded
  __shared__ float beta_s[NK];
  __shared__ float Ik[NK];

  const int tid = threadIdx.x;
  const float h = 1.0f / (float)M;

  // ---- issue W2 loads into regs (latency hides under layer-1) ----
  float4 wA = ((const float4*)W2)[tid];
  float4 wB = ((const float4*)W2)[tid + 512];

  // ---- layer 1: thread -> (knot = tid>>4, k0 = 4*(tid&15)), b128 write ----
  {
    const int knot = tid >> 4;                 // [0,32)
    const int k0   = (tid & 15) * 4;           // [0,64)
    const float tv = (float)knot * h;
    float4 w1 = *(const float4*)(W1 + k0);
    float4 bb = *(const float4*)(b1 + k0);
    float4 hv;
    hv.x = fast_tanhf(fmaf(tv, w1.x, bb.x));
    hv.y = fast_tanhf(fmaf(tv, w1.y, bb.y));
    hv.z = fast_tanhf(fmaf(tv, w1.z, bb.z));
    hv.w = fast_tanhf(fmaf(tv, w1.w, bb.w));
    *(float4*)(h1L + knot * H1S + k0) = hv;
  }

  // ---- complete W2 staging, then one barrier covers both ----
  ((float4*)W2s)[tid]       = wA;
  ((float4*)W2s)[tid + 512] = wB;
  __syncthreads();

  // ---- layers 2+3: thread -> (knot kg, units j0..j0+3) ----
  {
    const int kg = tid >> 4;            // [0,32)
    const int jq = tid & 15;
    const int j0 = jq * 4;
    float4 bb2 = *(const float4*)(b2 + j0);
    float z0 = bb2.x, z1 = bb2.y, z2 = bb2.z, z3 = bb2.w;
    const float* h1row = h1L + kg * H1S;
#pragma unroll 4
    for (int kc = 0; kc < HID; kc += 4) {
      float4 ha = *(const float4*)(h1row + kc);            // broadcast, no conflict
      float4 w0v = *(const float4*)(W2s + (kc + 0) * HID + j0);
      float4 w1v = *(const float4*)(W2s + (kc + 1) * HID + j0);
      float4 w2v = *(const float4*)(W2s + (kc + 2) * HID + j0);
      float4 w3v_ = *(const float4*)(W2s + (kc + 3) * HID + j0);
      z0 = fmaf(ha.x, w0v.x, z0); z1 = fmaf(ha.x, w0v.y, z1);
      z2 = fmaf(ha.x, w0v.z, z2); z3 = fmaf(ha.x, w0v.w, z3);
      z0 = fmaf(ha.y, w1v.x, z0); z1 = fmaf(ha.y, w1v.y, z1);
      z2 = fmaf(ha.y, w1v.z, z2); z3 = fmaf(ha.y, w1v.w, z3);
      z0 = fmaf(ha.z, w2v.x, z0); z1 = fmaf(ha.z, w2v.y, z1);
      z2 = fmaf(ha.z, w2v.z, z2); z3 = fmaf(ha.z, w2v.w, z3);
      z0 = fmaf(ha.w, w3v_.x, z0); z1 = fmaf(ha.w, w3v_.y, z1);
      z2 = fmaf(ha.w, w3v_.z, z2); z3 = fmaf(ha.w, w3v_.w, z3);
    }
    float4 w3v = *(const float4*)(W3 + j0);
    float acc = fast_tanhf(z0) * w3v.x + fast_tanhf(z1) * w3v.y
              + fast_tanhf(z2) * w3v.z + fast_tanhf(z3) * w3v.w;
    acc += __shfl_xor(acc, 1);
    acc += __shfl_xor(acc, 2);
    acc += __shfl_xor(acc, 4);
    acc += __shfl_xor(acc, 8);
    if (jq == 0) beta_s[kg] = softplusf(acc + b3[0]);
  }
  __syncthreads();

  // ---- Picard on half-wave 0 (lanes 0..31; serial path, others wait) ----
  if (tid < 32) {
    const float I0 = I_init[0];
    const float g  = softplusf(gamma_param[0]);
    const float S0 = 1.0f - I0;
    const int p = tid;
    const float tp = (float)p * h;
    const float bet = beta_s[p];
    const float c24 = h * (1.0f / 24.0f);
    float QA = 0.0f, QB = 0.0f;
    const int im2 = p >= 2 ? p - 2 : 0;
    const int im1 = p >= 1 ? p - 1 : 0;
    const int ip1 = p <= M - 1 ? p + 1 : M;
    const int ip2 = p <= M - 2 ? p + 2 : M;
    const int ip3 = p <= M - 3 ? p + 3 : M;
    for (int ph = 0; ph < 7; ++ph) {
      const bool iPass = (ph & 1) == 0;
      float f = iPass ? (bet * S0 * __expf(-QA))
                      : (bet * I0 * __expf(QB - g * tp));
      float fm2 = __shfl(f, im2);
      float fm1 = __shfl(f, im1);
      float f1  = __shfl(f, ip1);
      float f2  = __shfl(f, ip2);
      float f3  = __shfl(f, ip3);
      float e;
      if (p == 0)          e = 9.0f*f + 19.0f*f1 - 5.0f*f2 + f3;     // AM start
      else if (p < M - 1)  e = 13.0f*(f + f1) - fm1 - f2;            // interior
      else if (p == M - 1) e = fm2 - 5.0f*fm1 + 19.0f*f + 9.0f*f1;   // AM end
      else                 e = 0.0f;                                 // lane M
      e *= c24;
      float incl = e;
#pragma unroll
      for (int off = 1; off < 32; off <<= 1) {
        float w = __shfl_up(incl, off);
        if (p >= off) incl += w;
      }
      float Q = incl - e;                    // exclusive prefix = Q at knot p
      if (iPass) QB = Q; else QA = Q;
    }
    Ik[p] = I0 * __expf(QB - g * tp);        // I at knot p (exp folded here)
  }
  __syncthreads();

  // ---- output slice: cubic-Lagrange interp of Ik (no exp) ----
  const float scale = (float)M / (float)T;
  int o0 = blockIdx.x * OTILE + tid * OVPT;
  float r[OVPT];
#pragma unroll
  for (int u = 0; u < OVPT; ++u) {
    int i = o0 + u;
    float pos = (float)(i + 1) * scale;            // (0, M]
    int js = (int)pos - 1;
    js = js < 0 ? 0 : (js > M - 3 ? M - 3 : js);   // [0, 28]
    float x = pos - (float)js;                     // [0, 3]
    float xm1 = x - 1.0f, xm2 = x - 2.0f, xm3 = x - 3.0f;
    float w0 = -(xm1 * xm2 * xm3) * (1.0f / 6.0f);
    float w1 =  (x   * xm2 * xm3) * 0.5f;
    float w2 = -(x   * xm1 * xm3) * 0.5f;
    float w3 =  (x   * xm1 * xm2) * (1.0f / 6.0f);
    r[u] = w0 * Ik[js]     + w1 * Ik[js + 1]
         + w2 * Ik[js + 2] + w3 * Ik[js + 3];
  }
  if (o0 + OVPT <= T) {
    *(float4*)(out + o0) = make_float4(r[0], r[1], r[2], r[3]);
  } else {
#pragma unroll
    for (int u = 0; u < OVPT; ++u) {
      int i = o0 + u;
      if (i < T) out[i] = r[u];
    }
  }
}

extern "C" void kernel_launch(void* const* d_in, const int* in_sizes, int n_in,
                              void* d_out, int out_size, void* d_ws, size_t ws_size,
                              hipStream_t stream) {
  const float* I0 = (const float*)d_in[1];
  const float* W1 = (const float*)d_in[2];
  const float* b1 = (const float*)d_in[3];
  const float* W2 = (const float*)d_in[4];
  const float* b2 = (const float*)d_in[5];
  const float* W3 = (const float*)d_in[6];
  const float* b3 = (const float*)d_in[7];
  const float* gp = (const float*)d_in[8];
  float* out = (float*)d_out;
  int T = in_sizes[0];

  int blocks = (T + OTILE - 1) / OTILE;            // 245
  hipLaunchKernelGGL(sir_onekernel, dim3(blocks), dim3(TPB), 0, stream,
                     I0, W1, b1, W2, b2, W3, b3, gp, out, T);
}

// Round 14
// 11.290 us; speedup vs baseline: 1.3873x; 1.0710x over previous
//
#include <hip/hip_runtime.h>

static constexpr int HID = 64;
static constexpr int M   = 15;            // intervals; knots 0..15
static constexpr int NK  = 16;
static constexpr int H1S = 68;            // h1L stride: 64 + 4 pad (bank spread)
static constexpr int TPB = 512;           // 8 waves = 2/SIMD
static constexpr int OVPT  = 4;           // outputs per thread
static constexpr int OTILE = TPB * OVPT;  // 2048 outputs per block

__device__ __forceinline__ float softplusf(float x) {
  return (x > 20.0f) ? x : log1pf(expf(x));
}

// fast tanh via hardware exp + rcp: tanh(x) = 1 - 2/(e^{2x}+1). rel err ~1e-7.
__device__ __forceinline__ float fast_tanhf(float x) {
  float e = __expf(2.0f * x);
  return 1.0f - 2.0f * __builtin_amdgcn_rcpf(e + 1.0f);
}

// ONE kernel, 245 blocks x 512 threads — R13 structure with M halved to 15.
// (4th-order quadrature error <~2e-4 worst case, still 2.6x under threshold.)
//  1. W2 -> regs FIRST (HBM latency hides under layer-1), then ds_write.
//  2. layer 1 on threads 0..255: thread = (knot = tid>>4, k0 = 4*(tid&15)),
//     h1 stored transposed+padded h1L[knot*68+k], b128 writes.
//  3. layer2+3 on threads 0..255: thread = (knot kg, units j0..j0+3); per
//     4-k chunk: 1 h1 b128 broadcast + 4 W2 b128 (2-way aliased = free).
//  4. 16-lane Picard: 7 half-passes, 4th-order cumulative quadrature,
//     writes Ik[p] = I0*exp(Q_I(t_p) - g*t_p) to LDS.
//  5. all 512 threads: cubic-Lagrange interp of Ik (no exp), float4 stores.
__global__ void __launch_bounds__(TPB)
sir_onekernel(const float* __restrict__ I_init,
              const float* __restrict__ W1, const float* __restrict__ b1,
              const float* __restrict__ W2, const float* __restrict__ b2,
              const float* __restrict__ W3, const float* __restrict__ b3,
              const float* __restrict__ gamma_param,
              float* __restrict__ out, int T) {
  __shared__ float W2s[HID * HID];   // 16 KB
  __shared__ float h1L[NK * H1S];    // 4.3 KB, [knot][k] padded
  __shared__ float beta_s[NK];
  __shared__ float Ik[NK];

  const int tid = threadIdx.x;
  const float h = 1.0f / (float)M;

  // ---- issue W2 loads into regs (latency hides under layer-1) ----
  float4 wA = ((const float4*)W2)[tid];
  float4 wB = ((const float4*)W2)[tid + 512];

  // ---- layer 1 on threads 0..255: (knot = tid>>4, k0 = 4*(tid&15)) ----
  if (tid < 256) {
    const int knot = tid >> 4;                 // [0,16)
    const int k0   = (tid & 15) * 4;           // [0,64)
    const float tv = (float)knot * h;
    float4 w1 = *(const float4*)(W1 + k0);
    float4 bb = *(const float4*)(b1 + k0);
    float4 hv;
    hv.x = fast_tanhf(fmaf(tv, w1.x, bb.x));
    hv.y = fast_tanhf(fmaf(tv, w1.y, bb.y));
    hv.z = fast_tanhf(fmaf(tv, w1.z, bb.z));
    hv.w = fast_tanhf(fmaf(tv, w1.w, bb.w));
    *(float4*)(h1L + knot * H1S + k0) = hv;
  }

  // ---- complete W2 staging, then one barrier covers both ----
  ((float4*)W2s)[tid]       = wA;
  ((float4*)W2s)[tid + 512] = wB;
  __syncthreads();

  // ---- layers 2+3 on threads 0..255: (knot kg, units j0..j0+3) ----
  if (tid < 256) {
    const int kg = tid >> 4;            // [0,16)
    const int jq = tid & 15;
    const int j0 = jq * 4;
    float4 bb2 = *(const float4*)(b2 + j0);
    float z0 = bb2.x, z1 = bb2.y, z2 = bb2.z, z3 = bb2.w;
    const float* h1row = h1L + kg * H1S;
#pragma unroll 4
    for (int kc = 0; kc < HID; kc += 4) {
      float4 ha = *(const float4*)(h1row + kc);            // broadcast
      float4 w0v = *(const float4*)(W2s + (kc + 0) * HID + j0);
      float4 w1v = *(const float4*)(W2s + (kc + 1) * HID + j0);
      float4 w2v = *(const float4*)(W2s + (kc + 2) * HID + j0);
      float4 w3v_ = *(const float4*)(W2s + (kc + 3) * HID + j0);
      z0 = fmaf(ha.x, w0v.x, z0); z1 = fmaf(ha.x, w0v.y, z1);
      z2 = fmaf(ha.x, w0v.z, z2); z3 = fmaf(ha.x, w0v.w, z3);
      z0 = fmaf(ha.y, w1v.x, z0); z1 = fmaf(ha.y, w1v.y, z1);
      z2 = fmaf(ha.y, w1v.z, z2); z3 = fmaf(ha.y, w1v.w, z3);
      z0 = fmaf(ha.z, w2v.x, z0); z1 = fmaf(ha.z, w2v.y, z1);
      z2 = fmaf(ha.z, w2v.z, z2); z3 = fmaf(ha.z, w2v.w, z3);
      z0 = fmaf(ha.w, w3v_.x, z0); z1 = fmaf(ha.w, w3v_.y, z1);
      z2 = fmaf(ha.w, w3v_.z, z2); z3 = fmaf(ha.w, w3v_.w, z3);
    }
    float4 w3v = *(const float4*)(W3 + j0);
    float acc = fast_tanhf(z0) * w3v.x + fast_tanhf(z1) * w3v.y
              + fast_tanhf(z2) * w3v.z + fast_tanhf(z3) * w3v.w;
    acc += __shfl_xor(acc, 1);
    acc += __shfl_xor(acc, 2);
    acc += __shfl_xor(acc, 4);
    acc += __shfl_xor(acc, 8);
    if (jq == 0) beta_s[kg] = softplusf(acc + b3[0]);
  }
  __syncthreads();

  // ---- Picard on lanes 0..15 (serial path, others wait) ----
  if (tid < 16) {
    const float I0 = I_init[0];
    const float g  = softplusf(gamma_param[0]);
    const float S0 = 1.0f - I0;
    const int p = tid;
    const float tp = (float)p * h;
    const float bet = beta_s[p];
    const float c24 = h * (1.0f / 24.0f);
    float QA = 0.0f, QB = 0.0f;
    const int im2 = p >= 2 ? p - 2 : 0;
    const int im1 = p >= 1 ? p - 1 : 0;
    const int ip1 = p <= M - 1 ? p + 1 : M;
    const int ip2 = p <= M - 2 ? p + 2 : M;
    const int ip3 = p <= M - 3 ? p + 3 : M;
    for (int ph = 0; ph < 7; ++ph) {
      const bool iPass = (ph & 1) == 0;
      float f = iPass ? (bet * S0 * __expf(-QA))
                      : (bet * I0 * __expf(QB - g * tp));
      float fm2 = __shfl(f, im2);
      float fm1 = __shfl(f, im1);
      float f1  = __shfl(f, ip1);
      float f2  = __shfl(f, ip2);
      float f3  = __shfl(f, ip3);
      float e;
      if (p == 0)          e = 9.0f*f + 19.0f*f1 - 5.0f*f2 + f3;     // AM start
      else if (p < M - 1)  e = 13.0f*(f + f1) - fm1 - f2;            // interior
      else if (p == M - 1) e = fm2 - 5.0f*fm1 + 19.0f*f + 9.0f*f1;   // AM end
      else                 e = 0.0f;                                 // lane M
      e *= c24;
      float incl = e;
#pragma unroll
      for (int off = 1; off < 16; off <<= 1) {
        float w = __shfl_up(incl, off);
        if (p >= off) incl += w;
      }
      float Q = incl - e;                    // exclusive prefix = Q at knot p
      if (iPass) QB = Q; else QA = Q;
    }
    Ik[p] = I0 * __expf(QB - g * tp);        // I at knot p (exp folded here)
  }
  __syncthreads();

  // ---- output slice: cubic-Lagrange interp of Ik (no exp) ----
  const float scale = (float)M / (float)T;
  int o0 = blockIdx.x * OTILE + tid * OVPT;
  float r[OVPT];
#pragma unroll
  for (int u = 0; u < OVPT; ++u) {
    int i = o0 + u;
    float pos = (float)(i + 1) * scale;            // (0, M]
    int js = (int)pos - 1;
    js = js < 0 ? 0 : (js > M - 3 ? M - 3 : js);   // [0, 12]
    float x = pos - (float)js;                     // [0, 3]
    float xm1 = x - 1.0f, xm2 = x - 2.0f, xm3 = x - 3.0f;
    float w0 = -(xm1 * xm2 * xm3) * (1.0f / 6.0f);
    float w1 =  (x   * xm2 * xm3) * 0.5f;
    float w2 = -(x   * xm1 * xm3) * 0.5f;
    float w3 =  (x   * xm1 * xm2) * (1.0f / 6.0f);
    r[u] = w0 * Ik[js]     + w1 * Ik[js + 1]
         + w2 * Ik[js + 2] + w3 * Ik[js + 3];
  }
  if (o0 + OVPT <= T) {
    *(float4*)(out + o0) = make_float4(r[0], r[1], r[2], r[3]);
  } else {
#pragma unroll
    for (int u = 0; u < OVPT; ++u) {
      int i = o0 + u;
      if (i < T) out[i] = r[u];
    }
  }
}

extern "C" void kernel_launch(void* const* d_in, const int* in_sizes, int n_in,
                              void* d_out, int out_size, void* d_ws, size_t ws_size,
                              hipStream_t stream) {
  const float* I0 = (const float*)d_in[1];
  const float* W1 = (const float*)d_in[2];
  const float* b1 = (const float*)d_in[3];
  const float* W2 = (const float*)d_in[4];
  const float* b2 = (const float*)d_in[5];
  const float* W3 = (const float*)d_in[6];
  const float* b3 = (const float*)d_in[7];
  const float* gp = (const float*)d_in[8];
  float* out = (float*)d_out;
  int T = in_sizes[0];

  int blocks = (T + OTILE - 1) / OTILE;            // 245
  hipLaunchKernelGGL(sir_onekernel, dim3(blocks), dim3(TPB), 0, stream,
                     I0, W1, b1, W2, b2, W3, b3, gp, out, T);
}